// Round 11
// baseline (19374.152 us; speedup 1.0000x reference)
//
#include <hip/hip_runtime.h>
#include <stdint.h>

typedef short s16x8 __attribute__((ext_vector_type(8)));
typedef float f32x4 __attribute__((ext_vector_type(4)));
typedef uint32_t u32x2 __attribute__((ext_vector_type(2)));

#define LSEG 511

static __device__ __forceinline__ uint32_t cvt_pk_bf16(float lo, float hi) {
  uint32_t r;
  asm("v_cvt_pk_bf16_f32 %0, %1, %2" : "=v"(r) : "v"(lo), "v"(hi));
  return r;
}
static __device__ __forceinline__ unsigned short f2bf(float f) {
  union { float f; uint32_t u; } v; v.f = f;
  uint32_t r = (v.u + 0x7FFFu + ((v.u >> 16) & 1u)) >> 16;
  return (unsigned short)r;
}
// DPP row_ror:8 within 16-lane rows: lane lr <-> lr^8 (VALU pipe).
static __device__ __forceinline__ s16x8 dpp_swap8(s16x8 v) {
  union U { s16x8 s; int u[4]; } a, b;
  a.s = v;
  #pragma unroll
  for (int i = 0; i < 4; ++i)
    b.u[i] = __builtin_amdgcn_update_dpp(0, a.u[i], 0x128, 0xF, 0xF, false);
  return b.s;
}

// BT=8 twin-block design: 512 blocks of 8 batch rows -> 2 independent blocks
// per CU (4 waves/SIMD, two independent barrier domains = latency hiding).
// MFMA tiles are 16 cols with rows duplicated (lr and lr^8 = same batch row);
// LDS read doubling is cancelled by a kq-split: lane halves read DIFFERENT
// K-blocks (unique addresses, bank-uniform) and exchange fragments via
// row_ror:8 DPP + select. Per-wave LDS reads 15 -> 8.
// Swapped-operand MFMA (A=W^T, B=act^T), tanh prescale, bias C-in folding.
__global__ __attribute__((amdgpu_flat_work_group_size(512, 512),
                          amdgpu_waves_per_eu(4, 4)))
void cde_kernel(
    const float* __restrict__ coeffs,
    const float* __restrict__ W_init, const float* __restrict__ b_init,
    const float* __restrict__ W_in,  const float* __restrict__ b_in,
    const float* __restrict__ W_h,   const float* __restrict__ b_h,
    const float* __restrict__ W_out, const float* __restrict__ b_out,
    const float* __restrict__ W_read,const float* __restrict__ b_read,
    float* __restrict__ out)
{
  __shared__ __align__(16) char H1mem[8 * 256];
  __shared__ __align__(16) char H2mem[8 * 256];
  __shared__ __align__(16) char Xmem[8 * 128];
  __shared__ float dx2[4][8][8];        // [s][batch][c]

  const int tid  = threadIdx.x;
  const int w    = tid >> 6;     // wave 0..7
  const int lane = tid & 63;
  const int lr   = lane & 15;
  const int lrm  = lr & 7;       // batch row (twins lr>=8 duplicate)
  const bool tw  = lr >= 8;
  const int lk   = lane >> 4;
  const int b0   = blockIdx.x * 8;

  const float TS = 2.8853900817779268f;   // 2*log2(e)

  // ---- weight A-frags (A layout: row=lr, k=32*kq+8*lk+e) ----
  s16x8 Win_f[2], Wh0_f[4], Wh1_f[4], Wout_f[4][4];
  const int wc = 16*w + lr;
  #pragma unroll
  for (int kq = 0; kq < 2; ++kq)
    #pragma unroll
    for (int e = 0; e < 8; ++e)
      Win_f[kq][e] = (short)f2bf(W_in[(32*kq + 8*lk + e)*128 + wc]);
  #pragma unroll
  for (int kq = 0; kq < 4; ++kq)
    #pragma unroll
    for (int e = 0; e < 8; ++e) {
      Wh0_f[kq][e] = (short)f2bf(W_h[(32*kq + 8*lk + e)*128 + wc]);
      Wh1_f[kq][e] = (short)f2bf(W_h[16384 + (32*kq + 8*lk + e)*128 + wc]);
    }
  #pragma unroll
  for (int kq = 0; kq < 4; ++kq)
    #pragma unroll
    for (int nt = 0; nt < 4; ++nt) {
      const int ch = (8*w + 2*nt + ((lr >> 2) & 1))*8 + (lr & 3) + 4*((lr >> 3) & 1);
      #pragma unroll
      for (int e = 0; e < 8; ++e)
        Wout_f[kq][nt][e] = (short)f2bf(W_out[(32*kq + 8*lk + e)*512 + ch] * TS);
    }
  // per-row bias C-in vectors (D row = out-ch)
  f32x4 bin4, bh04, bh14, bout4[4];
  #pragma unroll
  for (int r = 0; r < 4; ++r) {
    bin4[r] = b_in[16*w + 4*lk + r];
    bh04[r] = b_h[16*w + 4*lk + r];
    bh14[r] = b_h[128 + 16*w + 4*lk + r];
  }
  #pragma unroll
  for (int nt = 0; nt < 4; ++nt)
    #pragma unroll
    for (int r = 0; r < 4; ++r)
      bout4[nt][r] = b_out[(8*w + 2*nt + (lk & 1))*8 + 4*(lk >> 1) + r] * TS;

  // ---- precomputed LDS byte offsets ----
  // H reads, kq-split: own half reads kqA = tw?2:0 and kqB = tw?3:1
  const int rbH0 = lrm*256 + (((4*(tw ? 2 : 0) + lk) ^ lrm) << 4);
  const int rbH1 = lrm*256 + (((4*(tw ? 3 : 1) + lk) ^ lrm) << 4);
  // X read, kq-split: own half reads kq = tw?1:0
  const int rbX = lrm*128 + ((((tw ? 4 : 0) + lk) ^ lrm) << 4);
  // H write (one b64, lanes !tw): batch=lrm, chs 16w+4lk..+3
  const int wbH = lrm*256 + (((2*w + (lk >> 1)) ^ lrm) << 4) + (lk & 1)*8;
  // X writes (4 b16, lanes lk<2 && !tw): h' = 2nt+(lk&1), blk=w
  int wbXh[4];
  #pragma unroll
  for (int nt = 0; nt < 4; ++nt)
    wbXh[nt] = lrm*128 + ((w ^ lrm) << 4) + 2*(2*nt + (lk & 1));
  const int dbx = lrm*32 + (lk >> 1)*16;   // dx2 read base: + s*256

  // ---- z0 init: lane owns batch lrm, h's {8w + 2nt + (lk&1)} ----
  float z0[4], zfin[4], k1r[4], k2r[4];
  {
    const float* a0r = &coeffs[(size_t)(b0 + lrm) * (LSEG*32)];
    #pragma unroll
    for (int nt = 0; nt < 4; ++nt) {
      const int h = 8*w + 2*nt + (lk & 1);
      float s = b_init[h];
      #pragma unroll
      for (int c = 0; c < 8; ++c) s = fmaf(a0r[c], W_init[c*64 + h], s);
      z0[nt] = s; zfin[nt] = 0.f; k1r[nt] = 0.f; k2r[nt] = 0.f;
    }
    if (lk < 2 && !tw) {
      #pragma unroll
      for (int nt = 0; nt < 4; ++nt)
        *(unsigned short*)(Xmem + wbXh[nt]) = (unsigned short)cvt_pk_bf16(z0[nt], z0[nt]);
    }
  }

  // ---- coeff prefetch regs: wave w -> batch row w, lanes 0..7 = c ----
  float cf_b = 0.f, cf_c = 0.f, cf_d = 0.f;
  const bool cact = lane < 8;
  if (cact) {
    const float* cp = &coeffs[(size_t)(b0 + w)*(LSEG*32)];
    cf_b = cp[8+lane]; cf_c = cp[16+lane]; cf_d = cp[24+lane];
  }
  __syncthreads();

  #pragma unroll 1
  for (int t = 0; t < LSEG; ++t) {
    #pragma unroll
    for (int s = 0; s < 4; ++s) {
      // =============== P1: (dx2 @ s==0) + L1: X -> H1 ===============
      if (s == 0 && cact) {
        const float third = 1.f/3.f, two3 = 2.f/3.f;
        float* dp = &dx2[0][w][lane];
        dp[0]   = cf_b;
        dp[64]  = fmaf(fmaf(cf_d, third, cf_c), third, cf_b);
        dp[128] = fmaf(fmaf(cf_d, two3, cf_c), two3, cf_b);
        dp[192] = cf_b + cf_c + cf_d;
        if (t + 1 < LSEG) {
          const float* cp = &coeffs[((size_t)(b0 + w)*LSEG + (t+1))*32];
          cf_b = cp[8+lane]; cf_c = cp[16+lane]; cf_d = cp[24+lane];
        }
      }
      {
        s16x8 r = *(const s16x8*)(Xmem + rbX);
        s16x8 tswap = dpp_swap8(r);
        s16x8 a0 = tw ? tswap : r;
        s16x8 a1 = tw ? r : tswap;
        __builtin_amdgcn_s_setprio(1);
        f32x4 acc;
        acc = __builtin_amdgcn_mfma_f32_16x16x32_bf16(Win_f[0], a0, bin4, 0, 0, 0);
        acc = __builtin_amdgcn_mfma_f32_16x16x32_bf16(Win_f[1], a1, acc, 0, 0, 0);
        __builtin_amdgcn_s_setprio(0);
        u32x2 pk;
        pk[0] = cvt_pk_bf16(fmaxf(acc[0], 0.f), fmaxf(acc[1], 0.f));
        pk[1] = cvt_pk_bf16(fmaxf(acc[2], 0.f), fmaxf(acc[3], 0.f));
        if (!tw) *(u32x2*)(H1mem + wbH) = pk;
      }
      __syncthreads();

      // =============== P2: L2: H1 -> H2 ===============
      {
        s16x8 r0 = *(const s16x8*)(H1mem + rbH0);
        s16x8 r1 = *(const s16x8*)(H1mem + rbH1);
        s16x8 t0 = dpp_swap8(r0);
        s16x8 t1 = dpp_swap8(r1);
        s16x8 a0 = tw ? t0 : r0;
        s16x8 a1 = tw ? t1 : r1;
        s16x8 a2 = tw ? r0 : t0;
        s16x8 a3 = tw ? r1 : t1;
        __builtin_amdgcn_s_setprio(1);
        f32x4 acc0, acc1 = {};
        acc0 = __builtin_amdgcn_mfma_f32_16x16x32_bf16(Wh0_f[0], a0, bh04, 0, 0, 0);
        acc1 = __builtin_amdgcn_mfma_f32_16x16x32_bf16(Wh0_f[1], a1, acc1, 0, 0, 0);
        acc0 = __builtin_amdgcn_mfma_f32_16x16x32_bf16(Wh0_f[2], a2, acc0, 0, 0, 0);
        acc1 = __builtin_amdgcn_mfma_f32_16x16x32_bf16(Wh0_f[3], a3, acc1, 0, 0, 0);
        __builtin_amdgcn_s_setprio(0);
        f32x4 acc = acc0 + acc1;
        u32x2 pk;
        pk[0] = cvt_pk_bf16(fmaxf(acc[0], 0.f), fmaxf(acc[1], 0.f));
        pk[1] = cvt_pk_bf16(fmaxf(acc[2], 0.f), fmaxf(acc[3], 0.f));
        if (!tw) *(u32x2*)(H2mem + wbH) = pk;
      }
      __syncthreads();

      // =============== P3: L3: H2 -> H1 ===============
      {
        s16x8 r0 = *(const s16x8*)(H2mem + rbH0);
        s16x8 r1 = *(const s16x8*)(H2mem + rbH1);
        s16x8 t0 = dpp_swap8(r0);
        s16x8 t1 = dpp_swap8(r1);
        s16x8 a0 = tw ? t0 : r0;
        s16x8 a1 = tw ? t1 : r1;
        s16x8 a2 = tw ? r0 : t0;
        s16x8 a3 = tw ? r1 : t1;
        __builtin_amdgcn_s_setprio(1);
        f32x4 acc0, acc1 = {};
        acc0 = __builtin_amdgcn_mfma_f32_16x16x32_bf16(Wh1_f[0], a0, bh14, 0, 0, 0);
        acc1 = __builtin_amdgcn_mfma_f32_16x16x32_bf16(Wh1_f[1], a1, acc1, 0, 0, 0);
        acc0 = __builtin_amdgcn_mfma_f32_16x16x32_bf16(Wh1_f[2], a2, acc0, 0, 0, 0);
        acc1 = __builtin_amdgcn_mfma_f32_16x16x32_bf16(Wh1_f[3], a3, acc1, 0, 0, 0);
        __builtin_amdgcn_s_setprio(0);
        f32x4 acc = acc0 + acc1;
        u32x2 pk;
        pk[0] = cvt_pk_bf16(fmaxf(acc[0], 0.f), fmaxf(acc[1], 0.f));
        pk[1] = cvt_pk_bf16(fmaxf(acc[2], 0.f), fmaxf(acc[3], 0.f));
        if (!tw) *(u32x2*)(H1mem + wbH) = pk;
      }
      __syncthreads();

      // ========= P4: L4 + tanh + einsum + RK state + X write =========
      {
        f32x4 dxv = *(const f32x4*)((const char*)dx2 + s*256 + dbx);
        s16x8 r0 = *(const s16x8*)(H1mem + rbH0);
        s16x8 r1 = *(const s16x8*)(H1mem + rbH1);
        s16x8 t0 = dpp_swap8(r0);
        s16x8 t1 = dpp_swap8(r1);
        s16x8 a0 = tw ? t0 : r0;
        s16x8 a1 = tw ? t1 : r1;
        s16x8 a2 = tw ? r0 : t0;
        s16x8 a3 = tw ? r1 : t1;
        __builtin_amdgcn_s_setprio(1);
        f32x4 acc[4];
        #pragma unroll
        for (int nt = 0; nt < 4; ++nt)
          acc[nt] = __builtin_amdgcn_mfma_f32_16x16x32_bf16(Wout_f[0][nt], a0, bout4[nt], 0, 0, 0);
        #pragma unroll
        for (int nt = 0; nt < 4; ++nt)
          acc[nt] = __builtin_amdgcn_mfma_f32_16x16x32_bf16(Wout_f[1][nt], a1, acc[nt], 0, 0, 0);
        #pragma unroll
        for (int nt = 0; nt < 4; ++nt)
          acc[nt] = __builtin_amdgcn_mfma_f32_16x16x32_bf16(Wout_f[2][nt], a2, acc[nt], 0, 0, 0);
        #pragma unroll
        for (int nt = 0; nt < 4; ++nt)
          acc[nt] = __builtin_amdgcn_mfma_f32_16x16x32_bf16(Wout_f[3][nt], a3, acc[nt], 0, 0, 0);
        __builtin_amdgcn_s_setprio(0);
        #pragma unroll
        for (int nt = 0; nt < 4; ++nt) {
          float sum = 0.f;
          #pragma unroll
          for (int r = 0; r < 4; ++r) {
            // acc pre-scaled by 2*log2(e): tanh = 1 - 2*rcp(exp2(acc)+1)
            float e2 = __builtin_amdgcn_exp2f(acc[nt][r]);
            float rr = __builtin_amdgcn_rcpf(e2 + 1.f);
            float tv = fmaf(-2.f, rr, 1.f);
            sum = fmaf(tv, dxv[r], sum);
          }
          sum += __shfl_xor(sum, 32);   // other c-half (lk^2, same batch/h)
          float znext;
          if (s == 0) {
            k1r[nt] = sum;
            zfin[nt] = fmaf(0.125f, sum, z0[nt]);
            znext    = fmaf(1.f/3.f, sum, z0[nt]);
          } else if (s == 1) {
            k2r[nt] = sum;
            zfin[nt] = fmaf(0.375f, sum, zfin[nt]);
            znext    = z0[nt] + sum - (1.f/3.f)*k1r[nt];
          } else if (s == 2) {
            zfin[nt] = fmaf(0.375f, sum, zfin[nt]);
            znext    = z0[nt] + k1r[nt] - k2r[nt] + sum;
          } else {
            zfin[nt] = fmaf(0.125f, sum, zfin[nt]);
            znext    = zfin[nt];
            z0[nt]   = zfin[nt];
          }
          if (lk < 2 && !tw)
            *(unsigned short*)(Xmem + wbXh[nt]) = (unsigned short)cvt_pk_bf16(znext, znext);
        }
      }
      __syncthreads();
    }
  }

  // ---- readout: stage z0 (fp32) into H1 bytes, then dot W_read ----
  float* ZF = (float*)H1mem;   // plain [8][64] floats
  if (lk < 2 && !tw) {
    #pragma unroll
    for (int nt = 0; nt < 4; ++nt)
      ZF[lrm*64 + 8*w + 2*nt + (lk & 1)] = z0[nt];
  }
  __syncthreads();
  if (tid < 8) {
    float acc = b_read[0];
    for (int h = 0; h < 64; ++h) acc = fmaf(ZF[tid*64 + h], W_read[h], acc);
    out[b0 + tid] = acc;
  }
}

extern "C" void kernel_launch(void* const* d_in, const int* in_sizes, int n_in,
                              void* d_out, int out_size, void* d_ws, size_t ws_size,
                              hipStream_t stream) {
  const float* coeffs = (const float*)d_in[0];
  const float* W_init = (const float*)d_in[1];
  const float* b_init = (const float*)d_in[2];
  const float* W_in   = (const float*)d_in[3];
  const float* b_in   = (const float*)d_in[4];
  const float* W_h    = (const float*)d_in[5];
  const float* b_h    = (const float*)d_in[6];
  const float* W_out  = (const float*)d_in[7];
  const float* b_out  = (const float*)d_in[8];
  const float* W_read = (const float*)d_in[9];
  const float* b_read = (const float*)d_in[10];
  float* out = (float*)d_out;

  cde_kernel<<<dim3(512), dim3(512), 0, stream>>>(
      coeffs, W_init, b_init, W_in, b_in, W_h, b_h, W_out, b_out,
      W_read, b_read, out);
}

// Round 12
// 2717.224 us; speedup vs baseline: 7.1301x; 7.1301x over previous
//
#include <hip/hip_runtime.h>
#include <stdint.h>

typedef short s16x8 __attribute__((ext_vector_type(8)));
typedef float f32x4 __attribute__((ext_vector_type(4)));
typedef uint32_t u32x2 __attribute__((ext_vector_type(2)));

#define LSEG 511

static __device__ __forceinline__ uint32_t cvt_pk_bf16(float lo, float hi) {
  uint32_t r;
  asm("v_cvt_pk_bf16_f32 %0, %1, %2" : "=v"(r) : "v"(lo), "v"(hi));
  return r;
}
static __device__ __forceinline__ unsigned short f2bf(float f) {
  union { float f; uint32_t u; } v; v.f = f;
  uint32_t r = (v.u + 0x7FFFu + ((v.u >> 16) & 1u)) >> 16;
  return (unsigned short)r;
}
// DPP row_ror:8 within 16 lanes: lr <-> lr^8 (VALU pipe, no DS traffic).
static __device__ __forceinline__ float dpp_xor8(float x) {
  return __int_as_float(__builtin_amdgcn_update_dpp(
      0, __float_as_int(x), 0x128, 0xF, 0xF, false));
}

// R8+R9 composition. 16 batch rows/block, 8 all-active waves, 1 block/CU
// (2 waves/SIMD — hard cap: weight-resident needs ~130 VGPR/wave; R10 proved
// 4 waves/EU spills catastrophically).
// P1-P3 (R9 style): OUT^T = W^T(A) · act^T(B); D col=batch, rows=4 contiguous
//   channels -> epilogue is 2 cvt_pk + ONE ds_write_b64, conflict-free.
// P4 (R8 style): act(A) · Wout(B) with c-major column permutation
//   (ch = 64w+8lc+2nt+hp): lane's 4 acc = 4 c's of one h; einsum = 4 fma +
//   dpp_xor8 (VALU); RK state (z0,zfin,k1,k2) in-lane for 2 rows.
// tanh prescale (W_out,b_out x 2log2e): tanh = 1 - 2*rcp(exp2(acc)+1).
__global__ __attribute__((amdgpu_flat_work_group_size(512, 512),
                          amdgpu_waves_per_eu(2, 2)))
void cde_kernel(
    const float* __restrict__ coeffs,
    const float* __restrict__ W_init, const float* __restrict__ b_init,
    const float* __restrict__ W_in,  const float* __restrict__ b_in,
    const float* __restrict__ W_h,   const float* __restrict__ b_h,
    const float* __restrict__ W_out, const float* __restrict__ b_out,
    const float* __restrict__ W_read,const float* __restrict__ b_read,
    float* __restrict__ out)
{
  __shared__ __align__(16) char H1mem[16 * 256];
  __shared__ __align__(16) char H2mem[16 * 256];
  __shared__ __align__(16) char Xmem[16 * 128];
  __shared__ float dx2[4][2][16][4];      // [s][hp][row][nt], c = 2*nt+hp

  const int tid  = threadIdx.x;
  const int w    = tid >> 6;     // wave 0..7
  const int lane = tid & 63;
  const int lr   = lane & 15;
  const int lk   = lane >> 4;
  const int lc   = lr & 7;
  const int hp   = lr >> 3;
  const int b0   = blockIdx.x * 16;
  const int h_own = 8*w + lc;    // lane's h in the P4 einsum

  const float TS = 2.8853900817779268f;   // 2*log2(e)

  // ---- weight frags (elem e = W[32*kq+8*lk+e][wc]; A-row / B-col = wc) ----
  s16x8 Win_f[2], Wh0_f[4], Wh1_f[4], Wout_f[4][4];
  const int wc = 16*w + lr;
  #pragma unroll
  for (int kq = 0; kq < 2; ++kq)
    #pragma unroll
    for (int e = 0; e < 8; ++e)
      Win_f[kq][e] = (short)f2bf(W_in[(32*kq + 8*lk + e)*128 + wc]);
  #pragma unroll
  for (int kq = 0; kq < 4; ++kq)
    #pragma unroll
    for (int e = 0; e < 8; ++e) {
      Wh0_f[kq][e] = (short)f2bf(W_h[(32*kq + 8*lk + e)*128 + wc]);
      Wh1_f[kq][e] = (short)f2bf(W_h[16384 + (32*kq + 8*lk + e)*128 + wc]);
    }
  // P4 Wout B-frags, c-major permutation (R8)
  #pragma unroll
  for (int kq = 0; kq < 4; ++kq)
    #pragma unroll
    for (int nt = 0; nt < 4; ++nt) {
      const int ch = 64*w + 8*lc + 2*nt + hp;
      #pragma unroll
      for (int e = 0; e < 8; ++e)
        Wout_f[kq][nt][e] = (short)f2bf(W_out[(32*kq + 8*lk + e)*512 + ch] * TS);
    }
  // P1-P3 biases: per-ROW C-in vectors (D row r = out-ch 16w+4lk+r)
  f32x4 bin4, bh04, bh14;
  #pragma unroll
  for (int r = 0; r < 4; ++r) {
    bin4[r] = b_in[16*w + 4*lk + r];
    bh04[r] = b_h[16*w + 4*lk + r];
    bh14[r] = b_h[128 + 16*w + 4*lk + r];
  }
  // P4 biases: splat (R8)
  f32x4 bout4[4];
  #pragma unroll
  for (int nt = 0; nt < 4; ++nt) {
    const float b = b_out[64*w + 8*lc + 2*nt + hp] * TS;
    bout4[nt] = (f32x4){b, b, b, b};
  }

  // ---- precomputed LDS byte offsets ----
  int vb[4];                       // H reads: row=lr(batch), blk=(4kq+lk)^swz
  #pragma unroll
  for (int kq = 0; kq < 4; ++kq)
    vb[kq] = lr*256 + (((4*kq + lk) ^ (lr & 7)) << 4);
  const int vbX0 = lr*128 + ((lk ^ (lr & 7)) << 4);
  const int vbX1 = vbX0 ^ 64;
  // P1-P3 write (one b64): batch=lr, chs 16w+4lk..+3
  const int wbH = lr*256 + (((2*w + (lk >> 1)) ^ (lr & 7)) << 4) + (lk & 1)*8;
  // P4 X writes (2 b16/lane): rows 4lk+2hp+{0,1}, ch h_own
  int wbX[2];
  #pragma unroll
  for (int j = 0; j < 2; ++j) {
    const int ro = 4*lk + 2*hp + j;
    wbX[j] = ro*128 + (((w ^ (ro & 7)) << 4)) + (lc << 1);
  }
  const int dbx = hp*256 + lk*64;  // dx2 read base: + s*512 + r*16

  // ---- z0 init: lane owns rows 4lk+2hp+{0,1}, channel h_own ----
  float z0[2], zfin[2], k1r[2], k2r[2];
  {
    float Wi[8];
    #pragma unroll
    for (int c = 0; c < 8; ++c) Wi[c] = W_init[c*64 + h_own];
    const float bi = b_init[h_own];
    #pragma unroll
    for (int j = 0; j < 2; ++j) {
      const int ro = 4*lk + 2*hp + j;
      const float* a0r = &coeffs[(size_t)(b0 + ro) * (LSEG*32)];
      float s = bi;
      #pragma unroll
      for (int c = 0; c < 8; ++c) s = fmaf(a0r[c], Wi[c], s);
      z0[j] = s; zfin[j] = 0.f; k1r[j] = 0.f; k2r[j] = 0.f;
      *(unsigned short*)(Xmem + wbX[j]) = f2bf(s);
    }
  }

  // ---- coeff prefetch regs: 16 lanes/wave ((lane&3)==0), 2 rows/wave ----
  float cf_b = 0.f, cf_c = 0.f, cf_d = 0.f;
  const int crow = 2*w + (lane >> 5);
  const int ccc  = (lane >> 2) & 7;
  const bool cact = (lane & 3) == 0;
  if (cact) {
    const float* cp = &coeffs[(size_t)(b0 + crow)*(LSEG*32)];
    cf_b = cp[8+ccc]; cf_c = cp[16+ccc]; cf_d = cp[24+ccc];
  }
  __syncthreads();

  #pragma unroll 1
  for (int t = 0; t < LSEG; ++t) {
    #pragma unroll
    for (int s = 0; s < 4; ++s) {
      // =============== P1: (dx2 @ s==0) + L1: X -> H1 ===============
      if (s == 0 && cact) {
        const float third = 1.f/3.f, two3 = 2.f/3.f;
        const int dxo = (ccc & 1)*256 + crow*16 + (ccc >> 1)*4;
        *(float*)((char*)dx2 + dxo)        = cf_b;
        *(float*)((char*)dx2 + dxo + 512)  = fmaf(fmaf(cf_d, third, cf_c), third, cf_b);
        *(float*)((char*)dx2 + dxo + 1024) = fmaf(fmaf(cf_d, two3, cf_c), two3, cf_b);
        *(float*)((char*)dx2 + dxo + 1536) = cf_b + cf_c + cf_d;
        if (t + 1 < LSEG) {
          const float* cp = &coeffs[((size_t)(b0 + crow)*LSEG + (t+1))*32];
          cf_b = cp[8+ccc]; cf_c = cp[16+ccc]; cf_d = cp[24+ccc];
        }
      }
      {
        s16x8 a0 = *(const s16x8*)(Xmem + vbX0);
        s16x8 a1 = *(const s16x8*)(Xmem + vbX1);
        __builtin_amdgcn_s_setprio(1);
        f32x4 acc;
        acc = __builtin_amdgcn_mfma_f32_16x16x32_bf16(Win_f[0], a0, bin4, 0, 0, 0);
        acc = __builtin_amdgcn_mfma_f32_16x16x32_bf16(Win_f[1], a1, acc, 0, 0, 0);
        __builtin_amdgcn_s_setprio(0);
        u32x2 pk;
        pk[0] = cvt_pk_bf16(fmaxf(acc[0], 0.f), fmaxf(acc[1], 0.f));
        pk[1] = cvt_pk_bf16(fmaxf(acc[2], 0.f), fmaxf(acc[3], 0.f));
        *(u32x2*)(H1mem + wbH) = pk;
      }
      __syncthreads();

      // =============== P2: L2: H1 -> H2 ===============
      {
        s16x8 a0 = *(const s16x8*)(H1mem + vb[0]);
        s16x8 a1 = *(const s16x8*)(H1mem + vb[1]);
        s16x8 a2 = *(const s16x8*)(H1mem + vb[2]);
        s16x8 a3 = *(const s16x8*)(H1mem + vb[3]);
        __builtin_amdgcn_s_setprio(1);
        f32x4 acc0, acc1 = {};
        acc0 = __builtin_amdgcn_mfma_f32_16x16x32_bf16(Wh0_f[0], a0, bh04, 0, 0, 0);
        acc1 = __builtin_amdgcn_mfma_f32_16x16x32_bf16(Wh0_f[1], a1, acc1, 0, 0, 0);
        acc0 = __builtin_amdgcn_mfma_f32_16x16x32_bf16(Wh0_f[2], a2, acc0, 0, 0, 0);
        acc1 = __builtin_amdgcn_mfma_f32_16x16x32_bf16(Wh0_f[3], a3, acc1, 0, 0, 0);
        __builtin_amdgcn_s_setprio(0);
        f32x4 acc = acc0 + acc1;
        u32x2 pk;
        pk[0] = cvt_pk_bf16(fmaxf(acc[0], 0.f), fmaxf(acc[1], 0.f));
        pk[1] = cvt_pk_bf16(fmaxf(acc[2], 0.f), fmaxf(acc[3], 0.f));
        *(u32x2*)(H2mem + wbH) = pk;
      }
      __syncthreads();

      // =============== P3: L3: H2 -> H1 ===============
      {
        s16x8 a0 = *(const s16x8*)(H2mem + vb[0]);
        s16x8 a1 = *(const s16x8*)(H2mem + vb[1]);
        s16x8 a2 = *(const s16x8*)(H2mem + vb[2]);
        s16x8 a3 = *(const s16x8*)(H2mem + vb[3]);
        __builtin_amdgcn_s_setprio(1);
        f32x4 acc0, acc1 = {};
        acc0 = __builtin_amdgcn_mfma_f32_16x16x32_bf16(Wh1_f[0], a0, bh14, 0, 0, 0);
        acc1 = __builtin_amdgcn_mfma_f32_16x16x32_bf16(Wh1_f[1], a1, acc1, 0, 0, 0);
        acc0 = __builtin_amdgcn_mfma_f32_16x16x32_bf16(Wh1_f[2], a2, acc0, 0, 0, 0);
        acc1 = __builtin_amdgcn_mfma_f32_16x16x32_bf16(Wh1_f[3], a3, acc1, 0, 0, 0);
        __builtin_amdgcn_s_setprio(0);
        f32x4 acc = acc0 + acc1;
        u32x2 pk;
        pk[0] = cvt_pk_bf16(fmaxf(acc[0], 0.f), fmaxf(acc[1], 0.f));
        pk[1] = cvt_pk_bf16(fmaxf(acc[2], 0.f), fmaxf(acc[3], 0.f));
        *(u32x2*)(H1mem + wbH) = pk;
      }
      __syncthreads();

      // ========= P4: L4 + tanh + einsum + RK state + X write =========
      {
        f32x4 dxv[4];
        #pragma unroll
        for (int r = 0; r < 4; ++r)
          dxv[r] = *(const f32x4*)((const char*)dx2 + dbx + s*512 + r*16);
        s16x8 a0 = *(const s16x8*)(H1mem + vb[0]);
        s16x8 a1 = *(const s16x8*)(H1mem + vb[1]);
        s16x8 a2 = *(const s16x8*)(H1mem + vb[2]);
        s16x8 a3 = *(const s16x8*)(H1mem + vb[3]);
        __builtin_amdgcn_s_setprio(1);
        f32x4 acc[4];
        #pragma unroll
        for (int nt = 0; nt < 4; ++nt)
          acc[nt] = __builtin_amdgcn_mfma_f32_16x16x32_bf16(a0, Wout_f[0][nt], bout4[nt], 0, 0, 0);
        #pragma unroll
        for (int nt = 0; nt < 4; ++nt)
          acc[nt] = __builtin_amdgcn_mfma_f32_16x16x32_bf16(a1, Wout_f[1][nt], acc[nt], 0, 0, 0);
        #pragma unroll
        for (int nt = 0; nt < 4; ++nt)
          acc[nt] = __builtin_amdgcn_mfma_f32_16x16x32_bf16(a2, Wout_f[2][nt], acc[nt], 0, 0, 0);
        #pragma unroll
        for (int nt = 0; nt < 4; ++nt)
          acc[nt] = __builtin_amdgcn_mfma_f32_16x16x32_bf16(a3, Wout_f[3][nt], acc[nt], 0, 0, 0);
        __builtin_amdgcn_s_setprio(0);
        float sums[4];
        #pragma unroll
        for (int r = 0; r < 4; ++r) {
          float sum = 0.f;
          #pragma unroll
          for (int nt = 0; nt < 4; ++nt) {
            // acc pre-scaled by 2*log2(e): tanh = 1 - 2*rcp(exp2(acc)+1)
            float e2 = __builtin_amdgcn_exp2f(acc[nt][r]);
            float rr = __builtin_amdgcn_rcpf(e2 + 1.f);
            float tv = fmaf(-2.f, rr, 1.f);
            sum = fmaf(tv, dxv[r][nt], sum);
          }
          sums[r] = sum + dpp_xor8(sum);   // full c-sum on both hp halves
        }
        #pragma unroll
        for (int j = 0; j < 2; ++j) {
          const float sum = sums[2*hp + j];
          float znext;
          if (s == 0) {
            k1r[j] = sum;
            zfin[j] = fmaf(0.125f, sum, z0[j]);
            znext   = fmaf(1.f/3.f, sum, z0[j]);
          } else if (s == 1) {
            k2r[j] = sum;
            zfin[j] = fmaf(0.375f, sum, zfin[j]);
            znext   = z0[j] + sum - (1.f/3.f)*k1r[j];
          } else if (s == 2) {
            zfin[j] = fmaf(0.375f, sum, zfin[j]);
            znext   = z0[j] + k1r[j] - k2r[j] + sum;
          } else {
            zfin[j] = fmaf(0.125f, sum, zfin[j]);
            znext   = zfin[j];
            z0[j]   = zfin[j];
          }
          *(unsigned short*)(Xmem + wbX[j]) = (unsigned short)cvt_pk_bf16(znext, znext);
        }
      }
      __syncthreads();
    }
  }

  // ---- readout: stage z0 (fp32) into H1 bytes, then dot W_read ----
  float* ZF = (float*)H1mem;   // plain [16][64] floats
  #pragma unroll
  for (int j = 0; j < 2; ++j)
    ZF[(4*lk + 2*hp + j)*64 + h_own] = z0[j];
  __syncthreads();
  if (tid < 16) {
    float acc = b_read[0];
    for (int h = 0; h < 64; ++h) acc = fmaf(ZF[tid*64 + h], W_read[h], acc);
    out[b0 + tid] = acc;
  }
}

extern "C" void kernel_launch(void* const* d_in, const int* in_sizes, int n_in,
                              void* d_out, int out_size, void* d_ws, size_t ws_size,
                              hipStream_t stream) {
  const float* coeffs = (const float*)d_in[0];
  const float* W_init = (const float*)d_in[1];
  const float* b_init = (const float*)d_in[2];
  const float* W_in   = (const float*)d_in[3];
  const float* b_in   = (const float*)d_in[4];
  const float* W_h    = (const float*)d_in[5];
  const float* b_h    = (const float*)d_in[6];
  const float* W_out  = (const float*)d_in[7];
  const float* b_out  = (const float*)d_in[8];
  const float* W_read = (const float*)d_in[9];
  const float* b_read = (const float*)d_in[10];
  float* out = (float*)d_out;

  cde_kernel<<<dim3(256), dim3(512), 0, stream>>>(
      coeffs, W_init, b_init, W_in, b_in, W_h, b_h, W_out, b_out,
      W_read, b_read, out);
}

// Round 13
// 2590.583 us; speedup vs baseline: 7.4787x; 1.0489x over previous
//
#include <hip/hip_runtime.h>
#include <stdint.h>

typedef short s16x8 __attribute__((ext_vector_type(8)));
typedef float f32x4 __attribute__((ext_vector_type(4)));
typedef uint32_t u32x2 __attribute__((ext_vector_type(2)));

#define LSEG 511

// In-loop barrier: LDS-only drain (no vmcnt!) so coeff-prefetch global loads
// stay in flight across phase barriers. Single asm => no memory op crosses.
#define LDS_BARRIER() asm volatile("s_waitcnt lgkmcnt(0)\n\ts_barrier" ::: "memory")

static __device__ __forceinline__ uint32_t cvt_pk_bf16(float lo, float hi) {
  uint32_t r;
  asm("v_cvt_pk_bf16_f32 %0, %1, %2" : "=v"(r) : "v"(lo), "v"(hi));
  return r;
}
static __device__ __forceinline__ unsigned short f2bf(float f) {
  union { float f; uint32_t u; } v; v.f = f;
  uint32_t r = (v.u + 0x7FFFu + ((v.u >> 16) & 1u)) >> 16;
  return (unsigned short)r;
}
// DPP row_ror:8 within 16 lanes: lr <-> lr^8 (VALU pipe, no DS traffic).
static __device__ __forceinline__ float dpp_xor8(float x) {
  return __int_as_float(__builtin_amdgcn_update_dpp(
      0, __float_as_int(x), 0x128, 0xF, 0xF, false));
}

// R11 structure (best: 2717us) + lgkmcnt-only barriers + leaner P4 exchange.
// 16 batch rows/block, 8 all-active waves, 1 block/CU (2 waves/SIMD hard cap:
// weight-resident needs ~130 VGPR/wave).
// P1-P3: OUT^T = W^T(A)·act^T(B); D col=batch, rows=4 contiguous channels ->
//   epilogue = 2 cvt_pk + ONE ds_write_b64.
// P4: act(A)·Wout(B), c-major cols (ch=64w+8lc+2nt+hp): lane's 4 acc = 4 c's
//   of one h; einsum = 4 fma + 2-dpp exchange; RK state in-lane (2 rows).
// tanh prescale (W_out,b_out x 2log2e): tanh = 1 - 2*rcp(exp2(acc)+1).
__global__ __attribute__((amdgpu_flat_work_group_size(512, 512),
                          amdgpu_waves_per_eu(2, 2)))
void cde_kernel(
    const float* __restrict__ coeffs,
    const float* __restrict__ W_init, const float* __restrict__ b_init,
    const float* __restrict__ W_in,  const float* __restrict__ b_in,
    const float* __restrict__ W_h,   const float* __restrict__ b_h,
    const float* __restrict__ W_out, const float* __restrict__ b_out,
    const float* __restrict__ W_read,const float* __restrict__ b_read,
    float* __restrict__ out)
{
  __shared__ __align__(16) char H1mem[16 * 256];
  __shared__ __align__(16) char H2mem[16 * 256];
  __shared__ __align__(16) char Xmem[16 * 128];
  __shared__ float dx2[4][2][16][4];      // [s][hp][row][nt], c = 2*nt+hp

  const int tid  = threadIdx.x;
  const int w    = tid >> 6;     // wave 0..7
  const int lane = tid & 63;
  const int lr   = lane & 15;
  const int lk   = lane >> 4;
  const int lc   = lr & 7;
  const int hp   = lr >> 3;
  const int b0   = blockIdx.x * 16;
  const int h_own = 8*w + lc;    // lane's h in the P4 einsum

  const float TS = 2.8853900817779268f;   // 2*log2(e)

  // ---- weight frags (elem e = W[32*kq+8*lk+e][wc]) ----
  s16x8 Win_f[2], Wh0_f[4], Wh1_f[4], Wout_f[4][4];
  const int wc = 16*w + lr;
  #pragma unroll
  for (int kq = 0; kq < 2; ++kq)
    #pragma unroll
    for (int e = 0; e < 8; ++e)
      Win_f[kq][e] = (short)f2bf(W_in[(32*kq + 8*lk + e)*128 + wc]);
  #pragma unroll
  for (int kq = 0; kq < 4; ++kq)
    #pragma unroll
    for (int e = 0; e < 8; ++e) {
      Wh0_f[kq][e] = (short)f2bf(W_h[(32*kq + 8*lk + e)*128 + wc]);
      Wh1_f[kq][e] = (short)f2bf(W_h[16384 + (32*kq + 8*lk + e)*128 + wc]);
    }
  #pragma unroll
  for (int kq = 0; kq < 4; ++kq)
    #pragma unroll
    for (int nt = 0; nt < 4; ++nt) {
      const int ch = 64*w + 8*lc + 2*nt + hp;
      #pragma unroll
      for (int e = 0; e < 8; ++e)
        Wout_f[kq][nt][e] = (short)f2bf(W_out[(32*kq + 8*lk + e)*512 + ch] * TS);
    }
  // P1-P3 biases: per-ROW C-in vectors (D row r = out-ch 16w+4lk+r)
  f32x4 bin4, bh04, bh14;
  #pragma unroll
  for (int r = 0; r < 4; ++r) {
    bin4[r] = b_in[16*w + 4*lk + r];
    bh04[r] = b_h[16*w + 4*lk + r];
    bh14[r] = b_h[128 + 16*w + 4*lk + r];
  }
  // P4 biases: splat
  f32x4 bout4[4];
  #pragma unroll
  for (int nt = 0; nt < 4; ++nt) {
    const float b = b_out[64*w + 8*lc + 2*nt + hp] * TS;
    bout4[nt] = (f32x4){b, b, b, b};
  }

  // ---- precomputed LDS byte offsets ----
  int vb[4];                       // H reads: row=lr(batch), blk=(4kq+lk)^swz
  #pragma unroll
  for (int kq = 0; kq < 4; ++kq)
    vb[kq] = lr*256 + (((4*kq + lk) ^ (lr & 7)) << 4);
  const int vbX0 = lr*128 + ((lk ^ (lr & 7)) << 4);
  const int vbX1 = vbX0 ^ 64;
  // P1-P3 write (one b64): batch=lr, chs 16w+4lk..+3
  const int wbH = lr*256 + (((2*w + (lk >> 1)) ^ (lr & 7)) << 4) + (lk & 1)*8;
  // P4 X writes (2 b16/lane): rows 4lk+2hp+{0,1}, ch h_own
  int wbX[2];
  #pragma unroll
  for (int j = 0; j < 2; ++j) {
    const int ro = 4*lk + 2*hp + j;
    wbX[j] = ro*128 + (((w ^ (ro & 7)) << 4)) + (lc << 1);
  }
  const int dbx = hp*256 + lk*64;  // dx2 read base: + s*512 + r*16

  // ---- z0 init: lane owns rows 4lk+2hp+{0,1}, channel h_own ----
  float z0[2], zfin[2], k1r[2], k2r[2];
  {
    float Wi[8];
    #pragma unroll
    for (int c = 0; c < 8; ++c) Wi[c] = W_init[c*64 + h_own];
    const float bi = b_init[h_own];
    #pragma unroll
    for (int j = 0; j < 2; ++j) {
      const int ro = 4*lk + 2*hp + j;
      const float* a0r = &coeffs[(size_t)(b0 + ro) * (LSEG*32)];
      float s = bi;
      #pragma unroll
      for (int c = 0; c < 8; ++c) s = fmaf(a0r[c], Wi[c], s);
      z0[j] = s; zfin[j] = 0.f; k1r[j] = 0.f; k2r[j] = 0.f;
      *(unsigned short*)(Xmem + wbX[j]) = f2bf(s);
    }
  }

  // ---- coeff prefetch regs: 16 lanes/wave ((lane&3)==0), 2 rows/wave ----
  float cf_b = 0.f, cf_c = 0.f, cf_d = 0.f;
  const int crow = 2*w + (lane >> 5);
  const int ccc  = (lane >> 2) & 7;
  const bool cact = (lane & 3) == 0;
  if (cact) {
    const float* cp = &coeffs[(size_t)(b0 + crow)*(LSEG*32)];
    cf_b = cp[8+ccc]; cf_c = cp[16+ccc]; cf_d = cp[24+ccc];
  }
  __syncthreads();

  #pragma unroll 1
  for (int t = 0; t < LSEG; ++t) {
    #pragma unroll
    for (int s = 0; s < 4; ++s) {
      // =============== P1: (dx2 @ s==0) + L1: X -> H1 ===============
      if (s == 0 && cact) {
        const float third = 1.f/3.f, two3 = 2.f/3.f;
        const int dxo = (ccc & 1)*256 + crow*16 + (ccc >> 1)*4;
        *(float*)((char*)dx2 + dxo)        = cf_b;
        *(float*)((char*)dx2 + dxo + 512)  = fmaf(fmaf(cf_d, third, cf_c), third, cf_b);
        *(float*)((char*)dx2 + dxo + 1024) = fmaf(fmaf(cf_d, two3, cf_c), two3, cf_b);
        *(float*)((char*)dx2 + dxo + 1536) = cf_b + cf_c + cf_d;
        if (t + 1 < LSEG) {  // stays in flight across LDS_BARRIERs
          const float* cp = &coeffs[((size_t)(b0 + crow)*LSEG + (t+1))*32];
          cf_b = cp[8+ccc]; cf_c = cp[16+ccc]; cf_d = cp[24+ccc];
        }
      }
      {
        s16x8 a0 = *(const s16x8*)(Xmem + vbX0);
        s16x8 a1 = *(const s16x8*)(Xmem + vbX1);
        __builtin_amdgcn_s_setprio(1);
        f32x4 acc;
        acc = __builtin_amdgcn_mfma_f32_16x16x32_bf16(Win_f[0], a0, bin4, 0, 0, 0);
        acc = __builtin_amdgcn_mfma_f32_16x16x32_bf16(Win_f[1], a1, acc, 0, 0, 0);
        __builtin_amdgcn_s_setprio(0);
        u32x2 pk;
        pk[0] = cvt_pk_bf16(fmaxf(acc[0], 0.f), fmaxf(acc[1], 0.f));
        pk[1] = cvt_pk_bf16(fmaxf(acc[2], 0.f), fmaxf(acc[3], 0.f));
        *(u32x2*)(H1mem + wbH) = pk;
      }
      LDS_BARRIER();

      // =============== P2: L2: H1 -> H2 ===============
      {
        s16x8 a0 = *(const s16x8*)(H1mem + vb[0]);
        s16x8 a1 = *(const s16x8*)(H1mem + vb[1]);
        s16x8 a2 = *(const s16x8*)(H1mem + vb[2]);
        s16x8 a3 = *(const s16x8*)(H1mem + vb[3]);
        __builtin_amdgcn_s_setprio(1);
        f32x4 acc0, acc1 = {};
        acc0 = __builtin_amdgcn_mfma_f32_16x16x32_bf16(Wh0_f[0], a0, bh04, 0, 0, 0);
        acc1 = __builtin_amdgcn_mfma_f32_16x16x32_bf16(Wh0_f[1], a1, acc1, 0, 0, 0);
        acc0 = __builtin_amdgcn_mfma_f32_16x16x32_bf16(Wh0_f[2], a2, acc0, 0, 0, 0);
        acc1 = __builtin_amdgcn_mfma_f32_16x16x32_bf16(Wh0_f[3], a3, acc1, 0, 0, 0);
        __builtin_amdgcn_s_setprio(0);
        f32x4 acc = acc0 + acc1;
        u32x2 pk;
        pk[0] = cvt_pk_bf16(fmaxf(acc[0], 0.f), fmaxf(acc[1], 0.f));
        pk[1] = cvt_pk_bf16(fmaxf(acc[2], 0.f), fmaxf(acc[3], 0.f));
        *(u32x2*)(H2mem + wbH) = pk;
      }
      LDS_BARRIER();

      // =============== P3: L3: H2 -> H1 ===============
      {
        s16x8 a0 = *(const s16x8*)(H2mem + vb[0]);
        s16x8 a1 = *(const s16x8*)(H2mem + vb[1]);
        s16x8 a2 = *(const s16x8*)(H2mem + vb[2]);
        s16x8 a3 = *(const s16x8*)(H2mem + vb[3]);
        __builtin_amdgcn_s_setprio(1);
        f32x4 acc0, acc1 = {};
        acc0 = __builtin_amdgcn_mfma_f32_16x16x32_bf16(Wh1_f[0], a0, bh14, 0, 0, 0);
        acc1 = __builtin_amdgcn_mfma_f32_16x16x32_bf16(Wh1_f[1], a1, acc1, 0, 0, 0);
        acc0 = __builtin_amdgcn_mfma_f32_16x16x32_bf16(Wh1_f[2], a2, acc0, 0, 0, 0);
        acc1 = __builtin_amdgcn_mfma_f32_16x16x32_bf16(Wh1_f[3], a3, acc1, 0, 0, 0);
        __builtin_amdgcn_s_setprio(0);
        f32x4 acc = acc0 + acc1;
        u32x2 pk;
        pk[0] = cvt_pk_bf16(fmaxf(acc[0], 0.f), fmaxf(acc[1], 0.f));
        pk[1] = cvt_pk_bf16(fmaxf(acc[2], 0.f), fmaxf(acc[3], 0.f));
        *(u32x2*)(H1mem + wbH) = pk;
      }
      LDS_BARRIER();

      // ========= P4: L4 + tanh + einsum + RK state + X write =========
      {
        // H reads first (feed the 16-MFMA chain), then dx2
        s16x8 a0 = *(const s16x8*)(H1mem + vb[0]);
        s16x8 a1 = *(const s16x8*)(H1mem + vb[1]);
        s16x8 a2 = *(const s16x8*)(H1mem + vb[2]);
        s16x8 a3 = *(const s16x8*)(H1mem + vb[3]);
        f32x4 dxv[4];
        #pragma unroll
        for (int r = 0; r < 4; ++r)
          dxv[r] = *(const f32x4*)((const char*)dx2 + dbx + s*512 + r*16);
        __builtin_amdgcn_s_setprio(1);
        f32x4 acc[4];
        #pragma unroll
        for (int nt = 0; nt < 4; ++nt)
          acc[nt] = __builtin_amdgcn_mfma_f32_16x16x32_bf16(a0, Wout_f[0][nt], bout4[nt], 0, 0, 0);
        #pragma unroll
        for (int nt = 0; nt < 4; ++nt)
          acc[nt] = __builtin_amdgcn_mfma_f32_16x16x32_bf16(a1, Wout_f[1][nt], acc[nt], 0, 0, 0);
        #pragma unroll
        for (int nt = 0; nt < 4; ++nt)
          acc[nt] = __builtin_amdgcn_mfma_f32_16x16x32_bf16(a2, Wout_f[2][nt], acc[nt], 0, 0, 0);
        #pragma unroll
        for (int nt = 0; nt < 4; ++nt)
          acc[nt] = __builtin_amdgcn_mfma_f32_16x16x32_bf16(a3, Wout_f[3][nt], acc[nt], 0, 0, 0);
        __builtin_amdgcn_s_setprio(0);
        float part[4];
        #pragma unroll
        for (int r = 0; r < 4; ++r) {
          float sum = 0.f;
          #pragma unroll
          for (int nt = 0; nt < 4; ++nt) {
            // acc pre-scaled by 2*log2(e): tanh = 1 - 2*rcp(exp2(acc)+1)
            float e2 = __builtin_amdgcn_exp2f(acc[nt][r]);
            float rr = __builtin_amdgcn_rcpf(e2 + 1.f);
            float tv = fmaf(-2.f, rr, 1.f);
            sum = fmaf(tv, dxv[r][nt], sum);
          }
          part[r] = sum;
        }
        #pragma unroll
        for (int j = 0; j < 2; ++j) {
          // exchange: send what partner (lr^8) needs, receive my missing half
          const float send = hp ? part[j] : part[2 + j];
          const float mine = hp ? part[2 + j] : part[j];
          const float sum  = mine + dpp_xor8(send);
          float znext;
          if (s == 0) {
            k1r[j] = sum;
            zfin[j] = fmaf(0.125f, sum, z0[j]);
            znext   = fmaf(1.f/3.f, sum, z0[j]);
          } else if (s == 1) {
            k2r[j] = sum;
            zfin[j] = fmaf(0.375f, sum, zfin[j]);
            znext   = z0[j] + sum - (1.f/3.f)*k1r[j];
          } else if (s == 2) {
            zfin[j] = fmaf(0.375f, sum, zfin[j]);
            znext   = z0[j] + k1r[j] - k2r[j] + sum;
          } else {
            zfin[j] = fmaf(0.125f, sum, zfin[j]);
            znext   = zfin[j];
            z0[j]   = zfin[j];
          }
          *(unsigned short*)(Xmem + wbX[j]) = (unsigned short)cvt_pk_bf16(znext, znext);
        }
      }
      LDS_BARRIER();
    }
  }

  // ---- readout: stage z0 (fp32) into H1 bytes, then dot W_read ----
  float* ZF = (float*)H1mem;   // plain [16][64] floats
  #pragma unroll
  for (int j = 0; j < 2; ++j)
    ZF[(4*lk + 2*hp + j)*64 + h_own] = z0[j];
  __syncthreads();
  if (tid < 16) {
    float acc = b_read[0];
    for (int h = 0; h < 64; ++h) acc = fmaf(ZF[tid*64 + h], W_read[h], acc);
    out[b0 + tid] = acc;
  }
}

extern "C" void kernel_launch(void* const* d_in, const int* in_sizes, int n_in,
                              void* d_out, int out_size, void* d_ws, size_t ws_size,
                              hipStream_t stream) {
  const float* coeffs = (const float*)d_in[0];
  const float* W_init = (const float*)d_in[1];
  const float* b_init = (const float*)d_in[2];
  const float* W_in   = (const float*)d_in[3];
  const float* b_in   = (const float*)d_in[4];
  const float* W_h    = (const float*)d_in[5];
  const float* b_h    = (const float*)d_in[6];
  const float* W_out  = (const float*)d_in[7];
  const float* b_out  = (const float*)d_in[8];
  const float* W_read = (const float*)d_in[9];
  const float* b_read = (const float*)d_in[10];
  float* out = (float*)d_out;

  cde_kernel<<<dim3(256), dim3(512), 0, stream>>>(
      coeffs, W_init, b_init, W_in, b_in, W_h, b_h, W_out, b_out,
      W_read, b_read, out);
}

// Round 14
// 2534.649 us; speedup vs baseline: 7.6437x; 1.0221x over previous
//
#include <hip/hip_runtime.h>
#include <stdint.h>

typedef short s16x8 __attribute__((ext_vector_type(8)));
typedef float f32x4 __attribute__((ext_vector_type(4)));
typedef uint32_t u32x2 __attribute__((ext_vector_type(2)));

#define LSEG 511

// In-loop barrier: LDS-only drain (no vmcnt!) so coeff-prefetch global loads
// stay in flight across phase barriers. Single asm => no memory op crosses.
#define LDS_BARRIER() asm volatile("s_waitcnt lgkmcnt(0)\n\ts_barrier" ::: "memory")

static __device__ __forceinline__ uint32_t cvt_pk_bf16(float lo, float hi) {
  uint32_t r;
  asm("v_cvt_pk_bf16_f32 %0, %1, %2" : "=v"(r) : "v"(lo), "v"(hi));
  return r;
}
static __device__ __forceinline__ unsigned short f2bf(float f) {
  union { float f; uint32_t u; } v; v.f = f;
  uint32_t r = (v.u + 0x7FFFu + ((v.u >> 16) & 1u)) >> 16;
  return (unsigned short)r;
}
// DPP row_ror:8 within 16 lanes: lr <-> lr^8 (VALU pipe, no DS traffic).
static __device__ __forceinline__ float dpp_xor8(float x) {
  return __int_as_float(__builtin_amdgcn_update_dpp(
      0, __float_as_int(x), 0x128, 0xF, 0xF, false));
}

// R12 structure (best: 2591us) + serial-tail trims:
//  - P4: nt-outer 4-deep MFMA chains; tanh/einsum per chain as it retires
//    (trans ops hidden under remaining MFMA issue); X write issued before
//    RK state bookkeeping (store-early).
//  - P1: X reads issued before dx2 VALU (read latency hidden).
// 16 batch rows/block, 8 all-active waves, 1 block/CU (2 waves/SIMD cap).
// P1-P3: OUT^T = W^T(A)·act^T(B); epilogue = 2 cvt_pk + ONE ds_write_b64.
// P4: act(A)·Wout(B), c-major cols; einsum = 4 fma + 2-dpp exchange.
// tanh prescale (W_out,b_out x 2log2e): tanh = 1 - 2*rcp(exp2(acc)+1).
__global__ __attribute__((amdgpu_flat_work_group_size(512, 512),
                          amdgpu_waves_per_eu(2, 2)))
void cde_kernel(
    const float* __restrict__ coeffs,
    const float* __restrict__ W_init, const float* __restrict__ b_init,
    const float* __restrict__ W_in,  const float* __restrict__ b_in,
    const float* __restrict__ W_h,   const float* __restrict__ b_h,
    const float* __restrict__ W_out, const float* __restrict__ b_out,
    const float* __restrict__ W_read,const float* __restrict__ b_read,
    float* __restrict__ out)
{
  __shared__ __align__(16) char H1mem[16 * 256];
  __shared__ __align__(16) char H2mem[16 * 256];
  __shared__ __align__(16) char Xmem[16 * 128];
  __shared__ float dx2[4][2][16][4];      // [s][hp][row][nt], c = 2*nt+hp

  const int tid  = threadIdx.x;
  const int w    = tid >> 6;     // wave 0..7
  const int lane = tid & 63;
  const int lr   = lane & 15;
  const int lk   = lane >> 4;
  const int lc   = lr & 7;
  const int hp   = lr >> 3;
  const int b0   = blockIdx.x * 16;
  const int h_own = 8*w + lc;    // lane's h in the P4 einsum

  const float TS = 2.8853900817779268f;   // 2*log2(e)

  // ---- weight frags (elem e = W[32*kq+8*lk+e][wc]) ----
  s16x8 Win_f[2], Wh0_f[4], Wh1_f[4], Wout_f[4][4];
  const int wc = 16*w + lr;
  #pragma unroll
  for (int kq = 0; kq < 2; ++kq)
    #pragma unroll
    for (int e = 0; e < 8; ++e)
      Win_f[kq][e] = (short)f2bf(W_in[(32*kq + 8*lk + e)*128 + wc]);
  #pragma unroll
  for (int kq = 0; kq < 4; ++kq)
    #pragma unroll
    for (int e = 0; e < 8; ++e) {
      Wh0_f[kq][e] = (short)f2bf(W_h[(32*kq + 8*lk + e)*128 + wc]);
      Wh1_f[kq][e] = (short)f2bf(W_h[16384 + (32*kq + 8*lk + e)*128 + wc]);
    }
  #pragma unroll
  for (int kq = 0; kq < 4; ++kq)
    #pragma unroll
    for (int nt = 0; nt < 4; ++nt) {
      const int ch = 64*w + 8*lc + 2*nt + hp;
      #pragma unroll
      for (int e = 0; e < 8; ++e)
        Wout_f[kq][nt][e] = (short)f2bf(W_out[(32*kq + 8*lk + e)*512 + ch] * TS);
    }
  // P1-P3 biases: per-ROW C-in vectors (D row r = out-ch 16w+4lk+r)
  f32x4 bin4, bh04, bh14;
  #pragma unroll
  for (int r = 0; r < 4; ++r) {
    bin4[r] = b_in[16*w + 4*lk + r];
    bh04[r] = b_h[16*w + 4*lk + r];
    bh14[r] = b_h[128 + 16*w + 4*lk + r];
  }
  // P4 biases: splat
  f32x4 bout4[4];
  #pragma unroll
  for (int nt = 0; nt < 4; ++nt) {
    const float b = b_out[64*w + 8*lc + 2*nt + hp] * TS;
    bout4[nt] = (f32x4){b, b, b, b};
  }

  // ---- precomputed LDS byte offsets ----
  int vb[4];                       // H reads: row=lr(batch), blk=(4kq+lk)^swz
  #pragma unroll
  for (int kq = 0; kq < 4; ++kq)
    vb[kq] = lr*256 + (((4*kq + lk) ^ (lr & 7)) << 4);
  const int vbX0 = lr*128 + ((lk ^ (lr & 7)) << 4);
  const int vbX1 = vbX0 ^ 64;
  // P1-P3 write (one b64): batch=lr, chs 16w+4lk..+3
  const int wbH = lr*256 + (((2*w + (lk >> 1)) ^ (lr & 7)) << 4) + (lk & 1)*8;
  // P4 X writes (2 b16/lane): rows 4lk+2hp+{0,1}, ch h_own
  int wbX[2];
  #pragma unroll
  for (int j = 0; j < 2; ++j) {
    const int ro = 4*lk + 2*hp + j;
    wbX[j] = ro*128 + (((w ^ (ro & 7)) << 4)) + (lc << 1);
  }
  const int dbx = hp*256 + lk*64;  // dx2 read base: + s*512 + r*16

  // ---- z0 init: lane owns rows 4lk+2hp+{0,1}, channel h_own ----
  float z0[2], zfin[2], k1r[2], k2r[2];
  {
    float Wi[8];
    #pragma unroll
    for (int c = 0; c < 8; ++c) Wi[c] = W_init[c*64 + h_own];
    const float bi = b_init[h_own];
    #pragma unroll
    for (int j = 0; j < 2; ++j) {
      const int ro = 4*lk + 2*hp + j;
      const float* a0r = &coeffs[(size_t)(b0 + ro) * (LSEG*32)];
      float s = bi;
      #pragma unroll
      for (int c = 0; c < 8; ++c) s = fmaf(a0r[c], Wi[c], s);
      z0[j] = s; zfin[j] = 0.f; k1r[j] = 0.f; k2r[j] = 0.f;
      *(unsigned short*)(Xmem + wbX[j]) = f2bf(s);
    }
  }

  // ---- coeff prefetch regs: 16 lanes/wave ((lane&3)==0), 2 rows/wave ----
  float cf_b = 0.f, cf_c = 0.f, cf_d = 0.f;
  const int crow = 2*w + (lane >> 5);
  const int ccc  = (lane >> 2) & 7;
  const bool cact = (lane & 3) == 0;
  if (cact) {
    const float* cp = &coeffs[(size_t)(b0 + crow)*(LSEG*32)];
    cf_b = cp[8+ccc]; cf_c = cp[16+ccc]; cf_d = cp[24+ccc];
  }
  __syncthreads();

  #pragma unroll 1
  for (int t = 0; t < LSEG; ++t) {
    #pragma unroll
    for (int s = 0; s < 4; ++s) {
      // =============== P1: X reads first, (dx2 @ s==0), L1 ===============
      {
        s16x8 a0 = *(const s16x8*)(Xmem + vbX0);   // issue reads first
        s16x8 a1 = *(const s16x8*)(Xmem + vbX1);
        if (s == 0 && cact) {                      // VALU under read latency
          const float third = 1.f/3.f, two3 = 2.f/3.f;
          const int dxo = (ccc & 1)*256 + crow*16 + (ccc >> 1)*4;
          *(float*)((char*)dx2 + dxo)        = cf_b;
          *(float*)((char*)dx2 + dxo + 512)  = fmaf(fmaf(cf_d, third, cf_c), third, cf_b);
          *(float*)((char*)dx2 + dxo + 1024) = fmaf(fmaf(cf_d, two3, cf_c), two3, cf_b);
          *(float*)((char*)dx2 + dxo + 1536) = cf_b + cf_c + cf_d;
          if (t + 1 < LSEG) {  // stays in flight across LDS_BARRIERs
            const float* cp = &coeffs[((size_t)(b0 + crow)*LSEG + (t+1))*32];
            cf_b = cp[8+ccc]; cf_c = cp[16+ccc]; cf_d = cp[24+ccc];
          }
        }
        __builtin_amdgcn_s_setprio(1);
        f32x4 acc;
        acc = __builtin_amdgcn_mfma_f32_16x16x32_bf16(Win_f[0], a0, bin4, 0, 0, 0);
        acc = __builtin_amdgcn_mfma_f32_16x16x32_bf16(Win_f[1], a1, acc, 0, 0, 0);
        __builtin_amdgcn_s_setprio(0);
        u32x2 pk;
        pk[0] = cvt_pk_bf16(fmaxf(acc[0], 0.f), fmaxf(acc[1], 0.f));
        pk[1] = cvt_pk_bf16(fmaxf(acc[2], 0.f), fmaxf(acc[3], 0.f));
        *(u32x2*)(H1mem + wbH) = pk;
      }
      LDS_BARRIER();

      // =============== P2: L2: H1 -> H2 ===============
      {
        s16x8 a0 = *(const s16x8*)(H1mem + vb[0]);
        s16x8 a1 = *(const s16x8*)(H1mem + vb[1]);
        s16x8 a2 = *(const s16x8*)(H1mem + vb[2]);
        s16x8 a3 = *(const s16x8*)(H1mem + vb[3]);
        __builtin_amdgcn_s_setprio(1);
        f32x4 acc0, acc1 = {};
        acc0 = __builtin_amdgcn_mfma_f32_16x16x32_bf16(Wh0_f[0], a0, bh04, 0, 0, 0);
        acc1 = __builtin_amdgcn_mfma_f32_16x16x32_bf16(Wh0_f[1], a1, acc1, 0, 0, 0);
        acc0 = __builtin_amdgcn_mfma_f32_16x16x32_bf16(Wh0_f[2], a2, acc0, 0, 0, 0);
        acc1 = __builtin_amdgcn_mfma_f32_16x16x32_bf16(Wh0_f[3], a3, acc1, 0, 0, 0);
        __builtin_amdgcn_s_setprio(0);
        f32x4 acc = acc0 + acc1;
        u32x2 pk;
        pk[0] = cvt_pk_bf16(fmaxf(acc[0], 0.f), fmaxf(acc[1], 0.f));
        pk[1] = cvt_pk_bf16(fmaxf(acc[2], 0.f), fmaxf(acc[3], 0.f));
        *(u32x2*)(H2mem + wbH) = pk;
      }
      LDS_BARRIER();

      // =============== P3: L3: H2 -> H1 ===============
      {
        s16x8 a0 = *(const s16x8*)(H2mem + vb[0]);
        s16x8 a1 = *(const s16x8*)(H2mem + vb[1]);
        s16x8 a2 = *(const s16x8*)(H2mem + vb[2]);
        s16x8 a3 = *(const s16x8*)(H2mem + vb[3]);
        __builtin_amdgcn_s_setprio(1);
        f32x4 acc0, acc1 = {};
        acc0 = __builtin_amdgcn_mfma_f32_16x16x32_bf16(Wh1_f[0], a0, bh14, 0, 0, 0);
        acc1 = __builtin_amdgcn_mfma_f32_16x16x32_bf16(Wh1_f[1], a1, acc1, 0, 0, 0);
        acc0 = __builtin_amdgcn_mfma_f32_16x16x32_bf16(Wh1_f[2], a2, acc0, 0, 0, 0);
        acc1 = __builtin_amdgcn_mfma_f32_16x16x32_bf16(Wh1_f[3], a3, acc1, 0, 0, 0);
        __builtin_amdgcn_s_setprio(0);
        f32x4 acc = acc0 + acc1;
        u32x2 pk;
        pk[0] = cvt_pk_bf16(fmaxf(acc[0], 0.f), fmaxf(acc[1], 0.f));
        pk[1] = cvt_pk_bf16(fmaxf(acc[2], 0.f), fmaxf(acc[3], 0.f));
        *(u32x2*)(H1mem + wbH) = pk;
      }
      LDS_BARRIER();

      // ========= P4: L4 + tanh + einsum + RK state + X write =========
      {
        s16x8 a0 = *(const s16x8*)(H1mem + vb[0]);
        s16x8 a1 = *(const s16x8*)(H1mem + vb[1]);
        s16x8 a2 = *(const s16x8*)(H1mem + vb[2]);
        s16x8 a3 = *(const s16x8*)(H1mem + vb[3]);
        f32x4 dxv[4];
        #pragma unroll
        for (int r = 0; r < 4; ++r)
          dxv[r] = *(const f32x4*)((const char*)dx2 + dbx + s*512 + r*16);
        // nt-outer: 4 independent 4-deep chains; tanh/einsum per chain as
        // it retires -> trans ops overlap remaining MFMA issue/latency.
        float part[4] = {0.f, 0.f, 0.f, 0.f};
        __builtin_amdgcn_s_setprio(1);
        #pragma unroll
        for (int nt = 0; nt < 4; ++nt) {
          f32x4 acc;
          acc = __builtin_amdgcn_mfma_f32_16x16x32_bf16(a0, Wout_f[0][nt], bout4[nt], 0, 0, 0);
          acc = __builtin_amdgcn_mfma_f32_16x16x32_bf16(a1, Wout_f[1][nt], acc, 0, 0, 0);
          acc = __builtin_amdgcn_mfma_f32_16x16x32_bf16(a2, Wout_f[2][nt], acc, 0, 0, 0);
          acc = __builtin_amdgcn_mfma_f32_16x16x32_bf16(a3, Wout_f[3][nt], acc, 0, 0, 0);
          #pragma unroll
          for (int r = 0; r < 4; ++r) {
            // acc pre-scaled by 2*log2(e): tanh = 1 - 2*rcp(exp2(acc)+1)
            float e2 = __builtin_amdgcn_exp2f(acc[r]);
            float rr = __builtin_amdgcn_rcpf(e2 + 1.f);
            float tv = fmaf(-2.f, rr, 1.f);
            part[r] = fmaf(tv, dxv[r][nt], part[r]);
          }
        }
        __builtin_amdgcn_s_setprio(0);
        #pragma unroll
        for (int j = 0; j < 2; ++j) {
          // exchange: send what partner (lr^8) needs, receive my missing half
          const float send = hp ? part[j] : part[2 + j];
          const float mine = hp ? part[2 + j] : part[j];
          const float sum  = mine + dpp_xor8(send);
          // store-early: znext -> write, then state bookkeeping
          float znext;
          if (s == 0)       znext = fmaf(1.f/3.f, sum, z0[j]);
          else if (s == 1)  znext = z0[j] + sum - (1.f/3.f)*k1r[j];
          else if (s == 2)  znext = z0[j] + k1r[j] - k2r[j] + sum;
          else              znext = fmaf(0.125f, sum, zfin[j]);
          *(unsigned short*)(Xmem + wbX[j]) = (unsigned short)cvt_pk_bf16(znext, znext);
          if (s == 0) {
            k1r[j] = sum;
            zfin[j] = fmaf(0.125f, sum, z0[j]);
          } else if (s == 1) {
            k2r[j] = sum;
            zfin[j] = fmaf(0.375f, sum, zfin[j]);
          } else if (s == 2) {
            zfin[j] = fmaf(0.375f, sum, zfin[j]);
          } else {
            zfin[j] = znext;
            z0[j]   = znext;
          }
        }
      }
      LDS_BARRIER();
    }
  }

  // ---- readout: stage z0 (fp32) into H1 bytes, then dot W_read ----
  float* ZF = (float*)H1mem;   // plain [16][64] floats
  #pragma unroll
  for (int j = 0; j < 2; ++j)
    ZF[(4*lk + 2*hp + j)*64 + h_own] = z0[j];
  __syncthreads();
  if (tid < 16) {
    float acc = b_read[0];
    for (int h = 0; h < 64; ++h) acc = fmaf(ZF[tid*64 + h], W_read[h], acc);
    out[b0 + tid] = acc;
  }
}

extern "C" void kernel_launch(void* const* d_in, const int* in_sizes, int n_in,
                              void* d_out, int out_size, void* d_ws, size_t ws_size,
                              hipStream_t stream) {
  const float* coeffs = (const float*)d_in[0];
  const float* W_init = (const float*)d_in[1];
  const float* b_init = (const float*)d_in[2];
  const float* W_in   = (const float*)d_in[3];
  const float* b_in   = (const float*)d_in[4];
  const float* W_h    = (const float*)d_in[5];
  const float* b_h    = (const float*)d_in[6];
  const float* W_out  = (const float*)d_in[7];
  const float* b_out  = (const float*)d_in[8];
  const float* W_read = (const float*)d_in[9];
  const float* b_read = (const float*)d_in[10];
  float* out = (float*)d_out;

  cde_kernel<<<dim3(256), dim3(512), 0, stream>>>(
      coeffs, W_init, b_init, W_in, b_in, W_h, b_h, W_out, b_out,
      W_read, b_read, out);
}